// Round 1
// baseline (668.847 us; speedup 1.0000x reference)
//
#include <hip/hip_runtime.h>

#define NN 16
#define BB 512
#define DD 256
#define RR (NN*BB)   // 8192

typedef __attribute__((ext_vector_type(8))) short v8s;
typedef __attribute__((ext_vector_type(4))) float v4f;

#define MFMA16(a,b,c) __builtin_amdgcn_mfma_f32_16x16x32_bf16((a),(b),(c),0,0,0)

__device__ __forceinline__ unsigned short f2bf(float f){
  unsigned int x = __float_as_uint(f);
  x += 0x7fffu + ((x >> 16) & 1u);
  return (unsigned short)(x >> 16);
}

// ---------- small prep kernels ----------

__global__ __launch_bounds__(256) void k_cast4(const float* __restrict__ in,
                                               unsigned short* __restrict__ out, int n4){
  int idx = blockIdx.x * 256 + threadIdx.x;
  if (idx < n4){
    float4 v = ((const float4*)in)[idx];
    ushort4 o;
    o.x = f2bf(v.x); o.y = f2bf(v.y); o.z = f2bf(v.z); o.w = f2bf(v.w);
    ((ushort4*)out)[idx] = o;
  }
}

// out[n*K + k] = bf16(in[k*Nin + n]) : transpose+cast, out is [N][K]
__global__ __launch_bounds__(256) void k_tc(const float* __restrict__ in,
                                            unsigned short* __restrict__ out,
                                            int kshift, int kmask, int nin, int total){
  int idx = blockIdx.x * 256 + threadIdx.x;
  if (idx < total){
    int n = idx >> kshift, k = idx & kmask;
    out[idx] = f2bf(in[k * nin + n]);
  }
}

// iW1abt [1024][256]: rows 0..511 = (iW1 top half)^T, rows 512..1023 = (iW1 bottom half)^T
__global__ __launch_bounds__(256) void k_iw1(const float* __restrict__ iW1,
                                             unsigned short* __restrict__ out){
  int idx = blockIdx.x * 256 + threadIdx.x;
  if (idx < 1024 * 256){
    int r = idx >> 8, k = idx & 255;
    float v = (r < 512) ? iW1[k * 512 + r] : iW1[(k + 256) * 512 + (r - 512)];
    out[idx] = f2bf(v);
  }
}

// ---------- phase-A GEMM ----------
// C[M][Nn] = act(A[M][KD] @ Wt[Nn][KD]^T + bias) (+ extra)
// tiles: BM=64, BN=128, BK=64; 256 threads; wave tile 32x64 (2x4 of 16x16)
template<int KD, bool OUTBF16, bool RELU, bool ADDX>
__global__ __launch_bounds__(256) void k_gemm(const unsigned short* __restrict__ A,
                                              const unsigned short* __restrict__ Wt,
                                              const float* __restrict__ bias,
                                              void* __restrict__ Cout,
                                              const float* __restrict__ extra,
                                              int M, int Nn){
  __shared__ __align__(16) unsigned char sA[64 * 128];   // [64 rows][64 k] bf16, swz
  __shared__ __align__(16) unsigned char sB[128 * 128];  // [128 n][64 k] bf16, swz
  const int m0 = blockIdx.x * 64;
  const int n0 = blockIdx.y * 128;
  const int t = threadIdx.x;
  const int w = t >> 6, l = t & 63;
  const int l15 = l & 15, lq = l >> 4;
  const int rowh = (w & 1) * 32, colh = (w >> 1) * 64;

  v4f c[2][4];
#pragma unroll
  for (int r = 0; r < 2; r++)
#pragma unroll
    for (int q = 0; q < 4; q++) c[r][q] = (v4f){0.f, 0.f, 0.f, 0.f};

  for (int kt = 0; kt < KD; kt += 64){
    __syncthreads();
    { // stage A tile
      const int row = t >> 2, cq = (t & 3) * 16;
      const unsigned short* src = A + (size_t)(m0 + row) * KD + kt + cq;
      v8s a0 = *(const v8s*)(src);
      v8s a1 = *(const v8s*)(src + 8);
      const unsigned sw = (unsigned)((row & 7) << 4);
      *(v8s*)(sA + ((unsigned)((row << 7) + (cq << 1)) ^ sw)) = a0;
      *(v8s*)(sA + ((unsigned)((row << 7) + (cq << 1) + 16) ^ sw)) = a1;
    }
    { // stage B tile
      const int n = t & 127, kq = (t >> 7) * 32;
      const unsigned short* src = Wt + (size_t)(n0 + n) * KD + kt + kq;
      const unsigned base = (unsigned)((n << 7) + (kq << 1));
      const unsigned sw = (unsigned)((n & 7) << 4);
#pragma unroll
      for (int q = 0; q < 4; q++){
        v8s v = *(const v8s*)(src + q * 8);
        *(v8s*)(sB + ((base + q * 16) ^ sw)) = v;
      }
    }
    __syncthreads();
#pragma unroll
    for (int kb = 0; kb < 64; kb += 32){
      v8s af[2], bfr[4];
#pragma unroll
      for (int r = 0; r < 2; r++){
        const int row = rowh + r * 16 + l15;
        af[r] = *(const v8s*)(sA + ((unsigned)((row << 7) + ((kb + (lq << 3)) << 1)) ^ (unsigned)((row & 7) << 4)));
      }
#pragma unroll
      for (int q = 0; q < 4; q++){
        const int n = colh + q * 16 + l15;
        bfr[q] = *(const v8s*)(sB + ((unsigned)((n << 7) + ((kb + (lq << 3)) << 1)) ^ (unsigned)((n & 7) << 4)));
      }
#pragma unroll
      for (int r = 0; r < 2; r++)
#pragma unroll
        for (int q = 0; q < 4; q++)
          c[r][q] = MFMA16(af[r], bfr[q], c[r][q]);
    }
  }
  // epilogue
#pragma unroll
  for (int r = 0; r < 2; r++){
#pragma unroll
    for (int q = 0; q < 4; q++){
      const int col = n0 + colh + q * 16 + l15;
      const float bv = bias ? bias[col] : 0.0f;
#pragma unroll
      for (int e = 0; e < 4; e++){
        const int row = m0 + rowh + r * 16 + (lq << 2) + e;
        float v = c[r][q][e] + bv;
        if (RELU) v = fmaxf(v, 0.0f);
        if (ADDX) v += extra[(size_t)row * Nn + col];
        if (OUTBF16) ((unsigned short*)Cout)[(size_t)row * Nn + col] = f2bf(v);
        else         ((float*)Cout)[(size_t)row * Nn + col] = v;
      }
    }
  }
}

// ---------- fused pair kernel ----------
// grid = 16 i * 16 row-tiles(32 rows) * 2 j-halves = 512 WGs, 256 threads (4 waves)
// per j in half (skip j==i):
//   A1 = relu(U_i + V_j + b1)            [32][512] bf16 LDS (swz)
//   A2 = relu(A1 @ W2 + b2)              [32][512] bf16 LDS (swz)
//   acc += relu(A2 @ W3 + b3)            registers
// epilogue: atomicAdd into out (out pre-initialized with trans+objs)
__global__ __launch_bounds__(256) void k_pair(const float* __restrict__ UV,           // [8192][1024] f32 (U | V+ib1? no: V raw)
                                              const unsigned short* __restrict__ W2t, // [512][512] bf16 (n,k)
                                              const unsigned short* __restrict__ W3t, // [256][512] bf16 (n,k)
                                              const float* __restrict__ b1,
                                              const float* __restrict__ b2,
                                              const float* __restrict__ b3,
                                              float* __restrict__ out){
  __shared__ __align__(16) unsigned char sA1[32 * 1024];
  __shared__ __align__(16) unsigned char sA2[32 * 1024];
  const int bid = blockIdx.x;
  const int i  = bid >> 5;
  const int rt = (bid >> 1) & 15;
  const int jh = bid & 1;
  const int t = threadIdx.x, w = t >> 6, l = t & 63;
  const int l15 = l & 15, lq = l >> 4;
  const int m0 = rt * 32;

  // A1-build mapping: 64 col-chunks of 8, 4 row-groups
  const int c8 = t & 63, rsub = t >> 6;

  float b1v[8];
#pragma unroll
  for (int e = 0; e < 8; e++) b1v[e] = b1[c8 * 8 + e];
  float b2v[8];
#pragma unroll
  for (int q = 0; q < 8; q++) b2v[q] = b2[w * 128 + q * 16 + l15];
  float b3v[4];
#pragma unroll
  for (int q = 0; q < 4; q++) b3v[q] = b3[w * 64 + q * 16 + l15];

  v4f acc[2][4];
#pragma unroll
  for (int r = 0; r < 2; r++)
#pragma unroll
    for (int q = 0; q < 4; q++) acc[r][q] = (v4f){0.f, 0.f, 0.f, 0.f};

  const float* Ubase = UV + (((size_t)(i * BB + m0)) << 10) + c8 * 8;

  for (int jj = 0; jj < 8; jj++){
    const int j = jh * 8 + jj;
    if (j == i) continue;          // block-uniform
    __syncthreads();               // prev GEMM2/3 readers done before overwrite

    { // build A1
      const float* Vbase = UV + (((size_t)(j * BB + m0)) << 10) + 512 + c8 * 8;
#pragma unroll
      for (int rr = 0; rr < 8; rr++){
        const int r = rsub + rr * 4;
        const float4* up = (const float4*)(Ubase + ((size_t)r << 10));
        const float4* vp = (const float4*)(Vbase + ((size_t)r << 10));
        float4 u0 = up[0], u1 = up[1];
        float4 v0 = vp[0], v1 = vp[1];
        v8s p;
        p[0] = (short)f2bf(fmaxf(u0.x + v0.x + b1v[0], 0.f));
        p[1] = (short)f2bf(fmaxf(u0.y + v0.y + b1v[1], 0.f));
        p[2] = (short)f2bf(fmaxf(u0.z + v0.z + b1v[2], 0.f));
        p[3] = (short)f2bf(fmaxf(u0.w + v0.w + b1v[3], 0.f));
        p[4] = (short)f2bf(fmaxf(u1.x + v1.x + b1v[4], 0.f));
        p[5] = (short)f2bf(fmaxf(u1.y + v1.y + b1v[5], 0.f));
        p[6] = (short)f2bf(fmaxf(u1.z + v1.z + b1v[6], 0.f));
        p[7] = (short)f2bf(fmaxf(u1.w + v1.w + b1v[7], 0.f));
        *(v8s*)(sA1 + ((unsigned)((r << 10) + (c8 << 4)) ^ (unsigned)((r & 7) << 4))) = p;
      }
    }
    __syncthreads();

    // GEMM2: c2[32][512] = A1 @ W2 ; wave owns cols w*128..+128
    v4f c2[2][8];
#pragma unroll
    for (int r = 0; r < 2; r++)
#pragma unroll
      for (int q = 0; q < 8; q++) c2[r][q] = (v4f){0.f, 0.f, 0.f, 0.f};
#pragma unroll 2
    for (int kb = 0; kb < 512; kb += 32){
      v8s af[2];
#pragma unroll
      for (int r = 0; r < 2; r++){
        const int row = r * 16 + l15;
        af[r] = *(const v8s*)(sA1 + ((unsigned)((row << 10) + ((kb + (lq << 3)) << 1)) ^ (unsigned)((row & 7) << 4)));
      }
#pragma unroll
      for (int q = 0; q < 8; q++){
        const int n = w * 128 + q * 16 + l15;
        v8s bfr = *(const v8s*)(W2t + ((size_t)n << 9) + kb + (lq << 3));
        c2[0][q] = MFMA16(af[0], bfr, c2[0][q]);
        c2[1][q] = MFMA16(af[1], bfr, c2[1][q]);
      }
    }
    // A2 = relu(c2 + b2) -> LDS bf16 (scalar b16 writes, swz keeps them consistent)
#pragma unroll
    for (int r = 0; r < 2; r++){
#pragma unroll
      for (int q = 0; q < 8; q++){
        const int col = w * 128 + q * 16 + l15;
#pragma unroll
        for (int e = 0; e < 4; e++){
          const int row = r * 16 + (lq << 2) + e;
          float v = fmaxf(c2[r][q][e] + b2v[q], 0.0f);
          *(unsigned short*)(sA2 + ((unsigned)((row << 10) + (col << 1)) ^ (unsigned)((row & 7) << 4))) = f2bf(v);
        }
      }
    }
    __syncthreads();

    // GEMM3: c3[32][256] = A2 @ W3 ; wave owns cols w*64..+64
    v4f c3[2][4];
#pragma unroll
    for (int r = 0; r < 2; r++)
#pragma unroll
      for (int q = 0; q < 4; q++) c3[r][q] = (v4f){0.f, 0.f, 0.f, 0.f};
#pragma unroll 2
    for (int kb = 0; kb < 512; kb += 32){
      v8s af[2];
#pragma unroll
      for (int r = 0; r < 2; r++){
        const int row = r * 16 + l15;
        af[r] = *(const v8s*)(sA2 + ((unsigned)((row << 10) + ((kb + (lq << 3)) << 1)) ^ (unsigned)((row & 7) << 4)));
      }
#pragma unroll
      for (int q = 0; q < 4; q++){
        const int n = w * 64 + q * 16 + l15;
        v8s bfr = *(const v8s*)(W3t + ((size_t)n << 9) + kb + (lq << 3));
        c3[0][q] = MFMA16(af[0], bfr, c3[0][q]);
        c3[1][q] = MFMA16(af[1], bfr, c3[1][q]);
      }
    }
    // acc += relu(c3 + b3)
#pragma unroll
    for (int r = 0; r < 2; r++)
#pragma unroll
      for (int q = 0; q < 4; q++)
#pragma unroll
        for (int e = 0; e < 4; e++)
          acc[r][q][e] += fmaxf(c3[r][q][e] + b3v[q], 0.0f);
  }

  // scatter-add into out
#pragma unroll
  for (int r = 0; r < 2; r++){
#pragma unroll
    for (int q = 0; q < 4; q++){
      const int col = w * 64 + q * 16 + l15;
#pragma unroll
      for (int e = 0; e < 4; e++){
        const int row = m0 + r * 16 + (lq << 2) + e;
        atomicAdd(out + (((size_t)(i * BB + row)) << 8) + col, acc[r][q][e]);
      }
    }
  }
}

// ---------- host ----------

extern "C" void kernel_launch(void* const* d_in, const int* in_sizes, int n_in,
                              void* d_out, int out_size, void* d_ws, size_t ws_size,
                              hipStream_t stream){
  const float* objs = (const float*)d_in[0];
  const float* tW1  = (const float*)d_in[1];
  const float* tb1  = (const float*)d_in[2];
  const float* tW2  = (const float*)d_in[3];
  const float* tb2  = (const float*)d_in[4];
  const float* tW3  = (const float*)d_in[5];
  const float* tb3  = (const float*)d_in[6];
  const float* iW1  = (const float*)d_in[7];
  const float* ib1  = (const float*)d_in[8];
  const float* iW2  = (const float*)d_in[9];
  const float* ib2  = (const float*)d_in[10];
  const float* iW3  = (const float*)d_in[11];
  const float* ib3  = (const float*)d_in[12];
  float* out = (float*)d_out;

  char* ws = (char*)d_ws;
  size_t off = 0;
  unsigned short* objsb  = (unsigned short*)(ws + off); off += (size_t)RR * DD * 2;        // 4 MB
  unsigned short* H1     = (unsigned short*)(ws + off); off += (size_t)RR * 512 * 2;       // 8 MB
  unsigned short* H2     = (unsigned short*)(ws + off); off += (size_t)RR * 512 * 2;       // 8 MB
  float*          UVb    = (float*)(ws + off);          off += (size_t)RR * 1024 * 4;      // 32 MB
  unsigned short* tW1t   = (unsigned short*)(ws + off); off += 512 * 256 * 2;
  unsigned short* tW2t   = (unsigned short*)(ws + off); off += 512 * 512 * 2;
  unsigned short* tW3t   = (unsigned short*)(ws + off); off += 256 * 512 * 2;
  unsigned short* iW1abt = (unsigned short*)(ws + off); off += 1024 * 256 * 2;
  unsigned short* iW2t   = (unsigned short*)(ws + off); off += 512 * 512 * 2;
  unsigned short* iW3t   = (unsigned short*)(ws + off); off += 256 * 512 * 2;
  (void)ws_size; (void)in_sizes; (void)n_in; (void)out_size;

  // casts / transposes
  k_cast4<<<dim3((RR * DD / 4 + 255) / 256), dim3(256), 0, stream>>>(objs, objsb, RR * DD / 4);
  k_tc<<<dim3(512),  dim3(256), 0, stream>>>(tW1, tW1t, 8, 255, 512, 512 * 256);
  k_tc<<<dim3(1024), dim3(256), 0, stream>>>(tW2, tW2t, 9, 511, 512, 512 * 512);
  k_tc<<<dim3(512),  dim3(256), 0, stream>>>(tW3, tW3t, 9, 511, 256, 256 * 512);
  k_tc<<<dim3(1024), dim3(256), 0, stream>>>(iW2, iW2t, 9, 511, 512, 512 * 512);
  k_tc<<<dim3(512),  dim3(256), 0, stream>>>(iW3, iW3t, 9, 511, 256, 256 * 512);
  k_iw1<<<dim3(1024), dim3(256), 0, stream>>>(iW1, iW1abt);

  // phase-A GEMMs
  k_gemm<256, true,  true,  false><<<dim3(RR / 64, 4), dim3(256), 0, stream>>>(objsb, tW1t, tb1, H1, nullptr, RR, 512);
  k_gemm<256, false, false, false><<<dim3(RR / 64, 8), dim3(256), 0, stream>>>(objsb, iW1abt, nullptr, UVb, nullptr, RR, 1024);
  k_gemm<512, true,  true,  false><<<dim3(RR / 64, 4), dim3(256), 0, stream>>>(H1, tW2t, tb2, H2, nullptr, RR, 512);
  // T path fused: out = relu(H2@tW3+tb3) + objs   (pair kernel then atomic-adds interact)
  k_gemm<512, false, true,  true ><<<dim3(RR / 64, 2), dim3(256), 0, stream>>>(H2, tW3t, tb3, d_out, objs, RR, DD);

  // fused pair interaction
  k_pair<<<dim3(512), dim3(256), 0, stream>>>(UVb, iW2t, iW3t, ib1, ib2, ib3, out);
}

// Round 2
// 326.417 us; speedup vs baseline: 2.0491x; 2.0491x over previous
//
#include <hip/hip_runtime.h>

#define NN 16
#define BB 512
#define DD 256
#define RR (NN*BB)   // 8192

typedef __attribute__((ext_vector_type(8))) short v8s;
typedef __attribute__((ext_vector_type(4))) float v4f;

#define MFMA16(a,b,c) __builtin_amdgcn_mfma_f32_16x16x32_bf16((a),(b),(c),0,0,0)

__device__ __forceinline__ unsigned short f2bf(float f){
  unsigned int x = __float_as_uint(f);
  x += 0x7fffu + ((x >> 16) & 1u);
  return (unsigned short)(x >> 16);
}
__device__ __forceinline__ float bf2f(unsigned short u){
  return __uint_as_float(((unsigned int)u) << 16);
}

// ---------- small prep kernels ----------

__global__ __launch_bounds__(256) void k_cast4(const float* __restrict__ in,
                                               unsigned short* __restrict__ out, int n4){
  int idx = blockIdx.x * 256 + threadIdx.x;
  if (idx < n4){
    float4 v = ((const float4*)in)[idx];
    ushort4 o;
    o.x = f2bf(v.x); o.y = f2bf(v.y); o.z = f2bf(v.z); o.w = f2bf(v.w);
    ((ushort4*)out)[idx] = o;
  }
}

// out[n*K + k] = bf16(in[k*Nin + n]) : transpose+cast, out is [N][K]
__global__ __launch_bounds__(256) void k_tc(const float* __restrict__ in,
                                            unsigned short* __restrict__ out,
                                            int kshift, int kmask, int nin, int total){
  int idx = blockIdx.x * 256 + threadIdx.x;
  if (idx < total){
    int n = idx >> kshift, k = idx & kmask;
    out[idx] = f2bf(in[k * nin + n]);
  }
}

// iW1abt [1024][256]: rows 0..511 = (iW1 top half)^T, rows 512..1023 = (iW1 bottom half)^T
__global__ __launch_bounds__(256) void k_iw1(const float* __restrict__ iW1,
                                             unsigned short* __restrict__ out){
  int idx = blockIdx.x * 256 + threadIdx.x;
  if (idx < 1024 * 256){
    int r = idx >> 8, k = idx & 255;
    float v = (r < 512) ? iW1[k * 512 + r] : iW1[(k + 256) * 512 + (r - 512)];
    out[idx] = f2bf(v);
  }
}

// extended bias for the UV gemm: 0 for U half, ib1 for V half
__global__ __launch_bounds__(256) void k_bias(const float* __restrict__ ib1,
                                              float* __restrict__ outb){
  int c = blockIdx.x * 256 + threadIdx.x;
  if (c < 1024) outb[c] = (c < 512) ? 0.f : ib1[c - 512];
}

// ---------- phase-A GEMM ----------
// C[M][Nn] = act(A[M][KD] @ Wt[Nn][KD]^T + bias) (+ extra)
// tiles: BM=64, BN=128, BK=64; 256 threads; wave tile 32x64 (2x4 of 16x16)
template<int KD, bool OUTBF16, bool RELU, bool ADDX>
__global__ __launch_bounds__(256) void k_gemm(const unsigned short* __restrict__ A,
                                              const unsigned short* __restrict__ Wt,
                                              const float* __restrict__ bias,
                                              void* __restrict__ Cout,
                                              const float* __restrict__ extra,
                                              int M, int Nn){
  __shared__ __align__(16) unsigned char sA[64 * 128];   // [64 rows][64 k] bf16, swz
  __shared__ __align__(16) unsigned char sB[128 * 128];  // [128 n][64 k] bf16, swz
  const int m0 = blockIdx.x * 64;
  const int n0 = blockIdx.y * 128;
  const int t = threadIdx.x;
  const int w = t >> 6, l = t & 63;
  const int l15 = l & 15, lq = l >> 4;
  const int rowh = (w & 1) * 32, colh = (w >> 1) * 64;

  v4f c[2][4];
#pragma unroll
  for (int r = 0; r < 2; r++)
#pragma unroll
    for (int q = 0; q < 4; q++) c[r][q] = (v4f){0.f, 0.f, 0.f, 0.f};

  for (int kt = 0; kt < KD; kt += 64){
    __syncthreads();
    { // stage A tile
      const int row = t >> 2, cq = (t & 3) * 16;
      const unsigned short* src = A + (size_t)(m0 + row) * KD + kt + cq;
      v8s a0 = *(const v8s*)(src);
      v8s a1 = *(const v8s*)(src + 8);
      const unsigned sw = (unsigned)((row & 7) << 4);
      *(v8s*)(sA + ((unsigned)((row << 7) + (cq << 1)) ^ sw)) = a0;
      *(v8s*)(sA + ((unsigned)((row << 7) + (cq << 1) + 16) ^ sw)) = a1;
    }
    { // stage B tile
      const int n = t & 127, kq = (t >> 7) * 32;
      const unsigned short* src = Wt + (size_t)(n0 + n) * KD + kt + kq;
      const unsigned base = (unsigned)((n << 7) + (kq << 1));
      const unsigned sw = (unsigned)((n & 7) << 4);
#pragma unroll
      for (int q = 0; q < 4; q++){
        v8s v = *(const v8s*)(src + q * 8);
        *(v8s*)(sB + ((base + q * 16) ^ sw)) = v;
      }
    }
    __syncthreads();
#pragma unroll
    for (int kb = 0; kb < 64; kb += 32){
      v8s af[2], bfr[4];
#pragma unroll
      for (int r = 0; r < 2; r++){
        const int row = rowh + r * 16 + l15;
        af[r] = *(const v8s*)(sA + ((unsigned)((row << 7) + ((kb + (lq << 3)) << 1)) ^ (unsigned)((row & 7) << 4)));
      }
#pragma unroll
      for (int q = 0; q < 4; q++){
        const int n = colh + q * 16 + l15;
        bfr[q] = *(const v8s*)(sB + ((unsigned)((n << 7) + ((kb + (lq << 3)) << 1)) ^ (unsigned)((n & 7) << 4)));
      }
#pragma unroll
      for (int r = 0; r < 2; r++)
#pragma unroll
        for (int q = 0; q < 4; q++)
          c[r][q] = MFMA16(af[r], bfr[q], c[r][q]);
    }
  }
  // epilogue
#pragma unroll
  for (int r = 0; r < 2; r++){
#pragma unroll
    for (int q = 0; q < 4; q++){
      const int col = n0 + colh + q * 16 + l15;
      const float bv = bias ? bias[col] : 0.0f;
#pragma unroll
      for (int e = 0; e < 4; e++){
        const int row = m0 + rowh + r * 16 + (lq << 2) + e;
        float v = c[r][q][e] + bv;
        if (RELU) v = fmaxf(v, 0.0f);
        if (ADDX) v += extra[(size_t)row * Nn + col];
        if (OUTBF16) ((unsigned short*)Cout)[(size_t)row * Nn + col] = f2bf(v);
        else         ((float*)Cout)[(size_t)row * Nn + col] = v;
      }
    }
  }
}

// ---------- fused pair kernel v2 ----------
// One WG = one (i,j) pair x 128 batch rows. 512 threads (8 waves), 144 KB LDS.
// Phase 1 (GEMM2, K=512, N=512): A1 tile [128x64] built on the fly from
//   bf16 U'(=objs@iW1top) and V'(=objs@iW1bot+ib1), reg-staged to LDS (swz);
//   W2 frags streamed from L2. MFMA operands SWAPPED (mfma(W2f, A1f)) so the
//   output frag's e-axis runs along n (= GEMM3's k): A2 packs as b64 writes
//   into [128 m][512 k] LDS, swizzled.
// Phase 2 (GEMM3, K=512, N=256): barrier-free loop, A2 from LDS, W3 from L2.
// Epilogue: atomicAdd relu(c3+b3) into out (pre-initialized with trans+objs).
__global__ __launch_bounds__(512, 2) void k_pair2(
    const unsigned short* __restrict__ UV,   // [8192][1024] bf16: cols 0..511=U', 512..1023=V'+ib1
    const unsigned short* __restrict__ W2t,  // [512][512] bf16 (n,k)
    const unsigned short* __restrict__ W3t,  // [256][512] bf16 (n,k)
    const float* __restrict__ b2,
    const float* __restrict__ b3,
    float* __restrict__ out){
  __shared__ __align__(16) unsigned char sA1[128 * 128];    // 16 KB  [128 m][64 k]
  __shared__ __align__(16) unsigned char sA2[128 * 1024];   // 128 KB [128 m][512 k]

  // bijective XCD swizzle (960 = 8*120), pairs i-major for U' L2 locality
  const int bid = blockIdx.x;
  const int wg  = (bid & 7) * 120 + (bid >> 3);
  const int p   = wg >> 2;               // pair 0..239
  const int q4  = wg & 3;                // 128-row quarter
  const int i   = p / 15;
  const int rj  = p - i * 15;
  const int j   = rj + (rj >= i ? 1 : 0);
  const int b0  = q4 * 128;

  const int t = threadIdx.x;
  const int w = t >> 6, l = t & 63, l15 = l & 15, lq = l >> 4;
  const int n0w = w * 64;

  const unsigned short* Up = UV + (((size_t)(i * BB + b0)) << 10);
  const unsigned short* Vp = UV + (((size_t)(j * BB + b0)) << 10) + 512;

  // staging map: thread -> row sr (0..127), k-quarter sk (0/16/32/48)
  const int sr = t >> 2, sk = (t & 3) << 4;
  const size_t srow = (size_t)sr << 10;
  const unsigned sbase = (unsigned)((sr << 7) + (sk << 1));
  const unsigned ssw = (unsigned)((sr & 7) << 4);

  v8s u0, u1, v0, v1;
  u0 = *(const v8s*)(Up + srow + sk);
  u1 = *(const v8s*)(Up + srow + sk + 8);
  v0 = *(const v8s*)(Vp + srow + sk);
  v1 = *(const v8s*)(Vp + srow + sk + 8);

  v4f c2[4][8];
#pragma unroll
  for (int nf = 0; nf < 4; nf++)
#pragma unroll
    for (int mf = 0; mf < 8; mf++) c2[nf][mf] = (v4f){0.f, 0.f, 0.f, 0.f};

  for (int kt = 0; kt < 512; kt += 64){
    if (kt) __syncthreads();             // all waves done reading prev A1 tile
    { // convert + write staged regs -> sA1
      v8s p0, p1;
#pragma unroll
      for (int e = 0; e < 8; e++){
        p0[e] = (short)f2bf(fmaxf(bf2f((unsigned short)u0[e]) + bf2f((unsigned short)v0[e]), 0.f));
        p1[e] = (short)f2bf(fmaxf(bf2f((unsigned short)u1[e]) + bf2f((unsigned short)v1[e]), 0.f));
      }
      *(v8s*)(sA1 + (sbase ^ ssw)) = p0;
      *(v8s*)(sA1 + ((sbase + 16) ^ ssw)) = p1;
    }
    __syncthreads();                     // A1 tile visible
    if (kt < 448){                       // issue next-tile loads early (T14)
      const int kn = kt + 64;
      u0 = *(const v8s*)(Up + srow + kn + sk);
      u1 = *(const v8s*)(Up + srow + kn + sk + 8);
      v0 = *(const v8s*)(Vp + srow + kn + sk);
      v1 = *(const v8s*)(Vp + srow + kn + sk + 8);
    }
#pragma unroll
    for (int kb = 0; kb < 64; kb += 32){
      v8s a1f[8], w2f[4];
#pragma unroll
      for (int mf = 0; mf < 8; mf++){
        const int row = mf * 16 + l15;
        a1f[mf] = *(const v8s*)(sA1 + ((unsigned)((row << 7) + ((kb + (lq << 3)) << 1)) ^ (unsigned)((row & 7) << 4)));
      }
#pragma unroll
      for (int nf = 0; nf < 4; nf++)
        w2f[nf] = *(const v8s*)(W2t + (((size_t)(n0w + nf * 16 + l15)) << 9) + kt + kb + (lq << 3));
#pragma unroll
      for (int nf = 0; nf < 4; nf++)
#pragma unroll
        for (int mf = 0; mf < 8; mf++)
          c2[nf][mf] = MFMA16(w2f[nf], a1f[mf], c2[nf][mf]);
    }
  }

  // A2 = relu(c2 + b2) -> sA2 [m][k] as packed b64 (e-axis is contiguous n)
#pragma unroll
  for (int nf = 0; nf < 4; nf++){
    const float4 bb = *(const float4*)(b2 + n0w + nf * 16 + (lq << 2));
#pragma unroll
    for (int mf = 0; mf < 8; mf++){
      v4f vv = c2[nf][mf];
      float x0 = fmaxf(vv[0] + bb.x, 0.f);
      float x1 = fmaxf(vv[1] + bb.y, 0.f);
      float x2 = fmaxf(vv[2] + bb.z, 0.f);
      float x3 = fmaxf(vv[3] + bb.w, 0.f);
      unsigned lo = (unsigned)f2bf(x0) | ((unsigned)f2bf(x1) << 16);
      unsigned hi = (unsigned)f2bf(x2) | ((unsigned)f2bf(x3) << 16);
      const int row = mf * 16 + l15;
      const unsigned addr = (unsigned)((row << 10) + ((n0w + nf * 16 + (lq << 2)) << 1)) ^ (unsigned)((row & 7) << 4);
      *(uint2*)(sA2 + addr) = make_uint2(lo, hi);
    }
  }
  __syncthreads();

  // GEMM3: barrier-free. wave grid 2m x 4n: rows wm*64.., cols wn*64..
  const int wm = w & 1, wn = w >> 1;
  v4f c3[4][4];
#pragma unroll
  for (int mf = 0; mf < 4; mf++)
#pragma unroll
    for (int nf = 0; nf < 4; nf++) c3[mf][nf] = (v4f){0.f, 0.f, 0.f, 0.f};

#pragma unroll 2
  for (int kb3 = 0; kb3 < 512; kb3 += 32){
    v8s a2f[4], w3f[4];
#pragma unroll
    for (int mf = 0; mf < 4; mf++){
      const int row = wm * 64 + mf * 16 + l15;
      a2f[mf] = *(const v8s*)(sA2 + ((unsigned)((row << 10) + ((kb3 + (lq << 3)) << 1)) ^ (unsigned)((row & 7) << 4)));
    }
#pragma unroll
    for (int nf = 0; nf < 4; nf++)
      w3f[nf] = *(const v8s*)(W3t + (((size_t)(wn * 64 + nf * 16 + l15)) << 9) + kb3 + (lq << 3));
#pragma unroll
    for (int mf = 0; mf < 4; mf++)
#pragma unroll
      for (int nf = 0; nf < 4; nf++)
        c3[mf][nf] = MFMA16(a2f[mf], w3f[nf], c3[mf][nf]);
  }

  // epilogue: interact contribution of pair (i,j) for rows b0+wm*64..+64
  float* obase = out + (((size_t)(i * BB + b0 + wm * 64)) << 8);
#pragma unroll
  for (int nf = 0; nf < 4; nf++){
    const int col = wn * 64 + nf * 16 + l15;
    const float b3v = b3[col];
#pragma unroll
    for (int mf = 0; mf < 4; mf++){
#pragma unroll
      for (int e = 0; e < 4; e++){
        const int row = mf * 16 + (lq << 2) + e;
        atomicAdd(obase + ((size_t)row << 8) + col, fmaxf(c3[mf][nf][e] + b3v, 0.f));
      }
    }
  }
}

// ---------- host ----------

extern "C" void kernel_launch(void* const* d_in, const int* in_sizes, int n_in,
                              void* d_out, int out_size, void* d_ws, size_t ws_size,
                              hipStream_t stream){
  const float* objs = (const float*)d_in[0];
  const float* tW1  = (const float*)d_in[1];
  const float* tb1  = (const float*)d_in[2];
  const float* tW2  = (const float*)d_in[3];
  const float* tb2  = (const float*)d_in[4];
  const float* tW3  = (const float*)d_in[5];
  const float* tb3  = (const float*)d_in[6];
  const float* iW1  = (const float*)d_in[7];
  const float* ib1  = (const float*)d_in[8];
  const float* ib2  = (const float*)d_in[10];
  const float* ib3  = (const float*)d_in[12];
  const float* iW2  = (const float*)d_in[9];
  const float* iW3  = (const float*)d_in[11];
  float* out = (float*)d_out;

  char* ws = (char*)d_ws;
  size_t off = 0;
  unsigned short* objsb  = (unsigned short*)(ws + off); off += (size_t)RR * DD * 2;        // 4 MB
  unsigned short* H1     = (unsigned short*)(ws + off); off += (size_t)RR * 512 * 2;       // 8 MB
  unsigned short* H2     = (unsigned short*)(ws + off); off += (size_t)RR * 512 * 2;       // 8 MB
  unsigned short* UVb    = (unsigned short*)(ws + off); off += (size_t)RR * 1024 * 2;      // 16 MB
  unsigned short* tW1t   = (unsigned short*)(ws + off); off += 512 * 256 * 2;
  unsigned short* tW2t   = (unsigned short*)(ws + off); off += 512 * 512 * 2;
  unsigned short* tW3t   = (unsigned short*)(ws + off); off += 256 * 512 * 2;
  unsigned short* iW1abt = (unsigned short*)(ws + off); off += 1024 * 256 * 2;
  unsigned short* iW2t   = (unsigned short*)(ws + off); off += 512 * 512 * 2;
  unsigned short* iW3t   = (unsigned short*)(ws + off); off += 256 * 512 * 2;
  float*          ib1ext = (float*)(ws + off);          off += 1024 * 4;
  (void)ws_size; (void)in_sizes; (void)n_in; (void)out_size;

  // casts / transposes
  k_cast4<<<dim3((RR * DD / 4 + 255) / 256), dim3(256), 0, stream>>>(objs, objsb, RR * DD / 4);
  k_tc<<<dim3(512),  dim3(256), 0, stream>>>(tW1, tW1t, 8, 255, 512, 512 * 256);
  k_tc<<<dim3(1024), dim3(256), 0, stream>>>(tW2, tW2t, 9, 511, 512, 512 * 512);
  k_tc<<<dim3(512),  dim3(256), 0, stream>>>(tW3, tW3t, 9, 511, 256, 256 * 512);
  k_tc<<<dim3(1024), dim3(256), 0, stream>>>(iW2, iW2t, 9, 511, 512, 512 * 512);
  k_tc<<<dim3(512),  dim3(256), 0, stream>>>(iW3, iW3t, 9, 511, 256, 256 * 512);
  k_iw1<<<dim3(1024), dim3(256), 0, stream>>>(iW1, iW1abt);
  k_bias<<<dim3(4),   dim3(256), 0, stream>>>(ib1, ib1ext);

  // phase-A GEMMs
  k_gemm<256, true,  true,  false><<<dim3(RR / 64, 4), dim3(256), 0, stream>>>(objsb, tW1t, tb1, H1, nullptr, RR, 512);
  // UV: bf16 out, bias = [0 | ib1] folded into V half, no relu
  k_gemm<256, true,  false, false><<<dim3(RR / 64, 8), dim3(256), 0, stream>>>(objsb, iW1abt, ib1ext, UVb, nullptr, RR, 1024);
  k_gemm<512, true,  true,  false><<<dim3(RR / 64, 4), dim3(256), 0, stream>>>(H1, tW2t, tb2, H2, nullptr, RR, 512);
  // T path fused: out = relu(H2@tW3+tb3) + objs   (pair kernel then atomic-adds interact)
  k_gemm<512, false, true,  true ><<<dim3(RR / 64, 2), dim3(256), 0, stream>>>(H2, tW3t, tb3, d_out, objs, RR, DD);

  // fused pair interaction
  k_pair2<<<dim3(960), dim3(512), 0, stream>>>(UVb, iW2t, iW3t, ib2, ib3, out);
}

// Round 3
// 271.216 us; speedup vs baseline: 2.4661x; 1.2035x over previous
//
#include <hip/hip_runtime.h>

#define NN 16
#define BB 512
#define DD 256
#define RR (NN*BB)   // 8192

typedef __attribute__((ext_vector_type(8))) short v8s;
typedef __attribute__((ext_vector_type(4))) float v4f;

#define MFMA16(a,b,c) __builtin_amdgcn_mfma_f32_16x16x32_bf16((a),(b),(c),0,0,0)

__device__ __forceinline__ unsigned short f2bf(float f){
  unsigned int x = __float_as_uint(f);
  x += 0x7fffu + ((x >> 16) & 1u);
  return (unsigned short)(x >> 16);
}
__device__ __forceinline__ float bf2f(unsigned short u){
  return __uint_as_float(((unsigned int)u) << 16);
}

// ---------- prep kernels ----------

__global__ __launch_bounds__(256) void k_cast4(const float* __restrict__ in,
                                               unsigned short* __restrict__ out, int n4){
  int idx = blockIdx.x * 256 + threadIdx.x;
  if (idx < n4){
    float4 v = ((const float4*)in)[idx];
    ushort4 o;
    o.x = f2bf(v.x); o.y = f2bf(v.y); o.z = f2bf(v.z); o.w = f2bf(v.w);
    ((ushort4*)out)[idx] = o;
  }
}

// all weight transposes + iW1 split + ib1ext in ONE launch (segment dispatch)
__global__ __launch_bounds__(256) void k_prep(
    const float* __restrict__ tW1, const float* __restrict__ tW2, const float* __restrict__ tW3,
    const float* __restrict__ iW1, const float* __restrict__ iW2, const float* __restrict__ iW3,
    const float* __restrict__ ib1,
    unsigned short* __restrict__ tW1t, unsigned short* __restrict__ tW2t, unsigned short* __restrict__ tW3t,
    unsigned short* __restrict__ iW1abt, unsigned short* __restrict__ iW2t, unsigned short* __restrict__ iW3t,
    float* __restrict__ ib1ext){
  int idx = blockIdx.x * 256 + threadIdx.x;
  if (idx < 131072){                                   // tW1t [512][256] <- tW1 [256][512]
    int n = idx >> 8, k = idx & 255;
    tW1t[idx] = f2bf(tW1[k * 512 + n]);
    return;
  }
  idx -= 131072;
  if (idx < 262144){                                   // tW2t [512][512]
    int n = idx >> 9, k = idx & 511;
    tW2t[idx] = f2bf(tW2[k * 512 + n]);
    return;
  }
  idx -= 262144;
  if (idx < 131072){                                   // tW3t [256][512] <- tW3 [512][256]
    int n = idx >> 9, k = idx & 511;
    tW3t[idx] = f2bf(tW3[k * 256 + n]);
    return;
  }
  idx -= 131072;
  if (idx < 262144){                                   // iW2t [512][512]
    int n = idx >> 9, k = idx & 511;
    iW2t[idx] = f2bf(iW2[k * 512 + n]);
    return;
  }
  idx -= 262144;
  if (idx < 131072){                                   // iW3t [256][512]
    int n = idx >> 9, k = idx & 511;
    iW3t[idx] = f2bf(iW3[k * 256 + n]);
    return;
  }
  idx -= 131072;
  if (idx < 262144){                                   // iW1abt [1024][256]
    int r = idx >> 8, k = idx & 255;
    float v = (r < 512) ? iW1[k * 512 + r] : iW1[(k + 256) * 512 + (r - 512)];
    iW1abt[idx] = f2bf(v);
    return;
  }
  idx -= 262144;
  if (idx < 1024)                                      // ib1ext: [0 | ib1]
    ib1ext[idx] = (idx < 512) ? 0.f : ib1[idx - 512];
}

// ---------- phase-A GEMM ----------
// C[M][Nn] = act(A[M][KD] @ Wt[Nn][KD]^T + bias) (+ extra)
template<int KD, bool OUTBF16, bool RELU, bool ADDX>
__global__ __launch_bounds__(256) void k_gemm(const unsigned short* __restrict__ A,
                                              const unsigned short* __restrict__ Wt,
                                              const float* __restrict__ bias,
                                              void* __restrict__ Cout,
                                              const float* __restrict__ extra,
                                              int M, int Nn){
  __shared__ __align__(16) unsigned char sA[64 * 128];
  __shared__ __align__(16) unsigned char sB[128 * 128];
  const int m0 = blockIdx.x * 64;
  const int n0 = blockIdx.y * 128;
  const int t = threadIdx.x;
  const int w = t >> 6, l = t & 63;
  const int l15 = l & 15, lq = l >> 4;
  const int rowh = (w & 1) * 32, colh = (w >> 1) * 64;

  v4f c[2][4];
#pragma unroll
  for (int r = 0; r < 2; r++)
#pragma unroll
    for (int q = 0; q < 4; q++) c[r][q] = (v4f){0.f, 0.f, 0.f, 0.f};

  for (int kt = 0; kt < KD; kt += 64){
    __syncthreads();
    {
      const int row = t >> 2, cq = (t & 3) * 16;
      const unsigned short* src = A + (size_t)(m0 + row) * KD + kt + cq;
      v8s a0 = *(const v8s*)(src);
      v8s a1 = *(const v8s*)(src + 8);
      const unsigned sw = (unsigned)((row & 7) << 4);
      *(v8s*)(sA + ((unsigned)((row << 7) + (cq << 1)) ^ sw)) = a0;
      *(v8s*)(sA + ((unsigned)((row << 7) + (cq << 1) + 16) ^ sw)) = a1;
    }
    {
      const int n = t & 127, kq = (t >> 7) * 32;
      const unsigned short* src = Wt + (size_t)(n0 + n) * KD + kt + kq;
      const unsigned base = (unsigned)((n << 7) + (kq << 1));
      const unsigned sw = (unsigned)((n & 7) << 4);
#pragma unroll
      for (int q = 0; q < 4; q++){
        v8s v = *(const v8s*)(src + q * 8);
        *(v8s*)(sB + ((base + q * 16) ^ sw)) = v;
      }
    }
    __syncthreads();
#pragma unroll
    for (int kb = 0; kb < 64; kb += 32){
      v8s af[2], bfr[4];
#pragma unroll
      for (int r = 0; r < 2; r++){
        const int row = rowh + r * 16 + l15;
        af[r] = *(const v8s*)(sA + ((unsigned)((row << 7) + ((kb + (lq << 3)) << 1)) ^ (unsigned)((row & 7) << 4)));
      }
#pragma unroll
      for (int q = 0; q < 4; q++){
        const int n = colh + q * 16 + l15;
        bfr[q] = *(const v8s*)(sB + ((unsigned)((n << 7) + ((kb + (lq << 3)) << 1)) ^ (unsigned)((n & 7) << 4)));
      }
#pragma unroll
      for (int r = 0; r < 2; r++)
#pragma unroll
        for (int q = 0; q < 4; q++)
          c[r][q] = MFMA16(af[r], bfr[q], c[r][q]);
    }
  }
#pragma unroll
  for (int r = 0; r < 2; r++){
#pragma unroll
    for (int q = 0; q < 4; q++){
      const int col = n0 + colh + q * 16 + l15;
      const float bv = bias ? bias[col] : 0.0f;
#pragma unroll
      for (int e = 0; e < 4; e++){
        const int row = m0 + rowh + r * 16 + (lq << 2) + e;
        float v = c[r][q][e] + bv;
        if (RELU) v = fmaxf(v, 0.0f);
        if (ADDX) v += extra[(size_t)row * Nn + col];
        if (OUTBF16) ((unsigned short*)Cout)[(size_t)row * Nn + col] = f2bf(v);
        else         ((float*)Cout)[(size_t)row * Nn + col] = v;
      }
    }
  }
}

// ---------- fused pair kernel ----------
// One WG = one (i,j) pair x 128 batch rows. 512 threads (8 waves), 144 KB LDS.
// Epilogue writes bf16 partial slab P[pair][512][256] with PLAIN stores
// (no atomics); k_reduce sums the 15 slabs per i afterwards.
__global__ __launch_bounds__(512, 2) void k_pair2(
    const unsigned short* __restrict__ UV,   // [8192][1024] bf16: U' | V'+ib1
    const unsigned short* __restrict__ W2t,  // [512][512] bf16 (n,k)
    const unsigned short* __restrict__ W3t,  // [256][512] bf16 (n,k)
    const float* __restrict__ b2,
    const float* __restrict__ b3,
    unsigned short* __restrict__ P){         // [240][512][256] bf16 partials
  __shared__ __align__(16) unsigned char sA1[128 * 128];    // 16 KB  [128 m][64 k]
  __shared__ __align__(16) unsigned char sA2[128 * 1024];   // 128 KB [128 m][512 k]

  const int bid = blockIdx.x;
  const int wg  = (bid & 7) * 120 + (bid >> 3);   // bijective XCD swizzle
  const int p   = wg >> 2;               // pair 0..239
  const int q4  = wg & 3;                // 128-row quarter
  const int i   = p / 15;
  const int rj  = p - i * 15;
  const int j   = rj + (rj >= i ? 1 : 0);
  const int b0  = q4 * 128;

  const int t = threadIdx.x;
  const int w = t >> 6, l = t & 63, l15 = l & 15, lq = l >> 4;
  const int n0w = w * 64;

  const unsigned short* Up = UV + (((size_t)(i * BB + b0)) << 10);
  const unsigned short* Vp = UV + (((size_t)(j * BB + b0)) << 10) + 512;

  const int sr = t >> 2, sk = (t & 3) << 4;
  const size_t srow = (size_t)sr << 10;
  const unsigned sbase = (unsigned)((sr << 7) + (sk << 1));
  const unsigned ssw = (unsigned)((sr & 7) << 4);

  v8s u0, u1, v0, v1;
  u0 = *(const v8s*)(Up + srow + sk);
  u1 = *(const v8s*)(Up + srow + sk + 8);
  v0 = *(const v8s*)(Vp + srow + sk);
  v1 = *(const v8s*)(Vp + srow + sk + 8);

  v4f c2[4][8];
#pragma unroll
  for (int nf = 0; nf < 4; nf++)
#pragma unroll
    for (int mf = 0; mf < 8; mf++) c2[nf][mf] = (v4f){0.f, 0.f, 0.f, 0.f};

  for (int kt = 0; kt < 512; kt += 64){
    if (kt) __syncthreads();
    { // convert staged regs -> sA1
      v8s p0, p1;
#pragma unroll
      for (int e = 0; e < 8; e++){
        p0[e] = (short)f2bf(fmaxf(bf2f((unsigned short)u0[e]) + bf2f((unsigned short)v0[e]), 0.f));
        p1[e] = (short)f2bf(fmaxf(bf2f((unsigned short)u1[e]) + bf2f((unsigned short)v1[e]), 0.f));
      }
      *(v8s*)(sA1 + (sbase ^ ssw)) = p0;
      *(v8s*)(sA1 + ((sbase + 16) ^ ssw)) = p1;
    }
    __syncthreads();
    if (kt < 448){                       // prefetch next tile (T14)
      const int kn = kt + 64;
      u0 = *(const v8s*)(Up + srow + kn + sk);
      u1 = *(const v8s*)(Up + srow + kn + sk + 8);
      v0 = *(const v8s*)(Vp + srow + kn + sk);
      v1 = *(const v8s*)(Vp + srow + kn + sk + 8);
    }
#pragma unroll
    for (int kb = 0; kb < 64; kb += 32){
      v8s a1f[8], w2f[4];
#pragma unroll
      for (int nf = 0; nf < 4; nf++)
        w2f[nf] = *(const v8s*)(W2t + (((size_t)(n0w + nf * 16 + l15)) << 9) + kt + kb + (lq << 3));
#pragma unroll
      for (int mf = 0; mf < 8; mf++){
        const int row = mf * 16 + l15;
        a1f[mf] = *(const v8s*)(sA1 + ((unsigned)((row << 7) + ((kb + (lq << 3)) << 1)) ^ (unsigned)((row & 7) << 4)));
      }
      __builtin_amdgcn_s_setprio(1);
#pragma unroll
      for (int nf = 0; nf < 4; nf++)
#pragma unroll
        for (int mf = 0; mf < 8; mf++)
          c2[nf][mf] = MFMA16(w2f[nf], a1f[mf], c2[nf][mf]);
      __builtin_amdgcn_s_setprio(0);
    }
  }

  // A2 = relu(c2 + b2) -> sA2 [m][k] packed b64
#pragma unroll
  for (int nf = 0; nf < 4; nf++){
    const float4 bb = *(const float4*)(b2 + n0w + nf * 16 + (lq << 2));
#pragma unroll
    for (int mf = 0; mf < 8; mf++){
      v4f vv = c2[nf][mf];
      float x0 = fmaxf(vv[0] + bb.x, 0.f);
      float x1 = fmaxf(vv[1] + bb.y, 0.f);
      float x2 = fmaxf(vv[2] + bb.z, 0.f);
      float x3 = fmaxf(vv[3] + bb.w, 0.f);
      unsigned lo = (unsigned)f2bf(x0) | ((unsigned)f2bf(x1) << 16);
      unsigned hi = (unsigned)f2bf(x2) | ((unsigned)f2bf(x3) << 16);
      const int row = mf * 16 + l15;
      const unsigned addr = (unsigned)((row << 10) + ((n0w + nf * 16 + (lq << 2)) << 1)) ^ (unsigned)((row & 7) << 4);
      *(uint2*)(sA2 + addr) = make_uint2(lo, hi);
    }
  }
  __syncthreads();

  // GEMM3: barrier-free. wave grid 2m x 4n
  const int wm = w & 1, wn = w >> 1;
  v4f c3[4][4];
#pragma unroll
  for (int mf = 0; mf < 4; mf++)
#pragma unroll
    for (int nf = 0; nf < 4; nf++) c3[mf][nf] = (v4f){0.f, 0.f, 0.f, 0.f};

#pragma unroll 2
  for (int kb3 = 0; kb3 < 512; kb3 += 32){
    v8s a2f[4], w3f[4];
#pragma unroll
    for (int nf = 0; nf < 4; nf++)
      w3f[nf] = *(const v8s*)(W3t + (((size_t)(wn * 64 + nf * 16 + l15)) << 9) + kb3 + (lq << 3));
#pragma unroll
    for (int mf = 0; mf < 4; mf++){
      const int row = wm * 64 + mf * 16 + l15;
      a2f[mf] = *(const v8s*)(sA2 + ((unsigned)((row << 10) + ((kb3 + (lq << 3)) << 1)) ^ (unsigned)((row & 7) << 4)));
    }
    __builtin_amdgcn_s_setprio(1);
#pragma unroll
    for (int mf = 0; mf < 4; mf++)
#pragma unroll
      for (int nf = 0; nf < 4; nf++)
        c3[mf][nf] = MFMA16(a2f[mf], w3f[nf], c3[mf][nf]);
    __builtin_amdgcn_s_setprio(0);
  }

  // epilogue: plain bf16 stores into pair slab
  unsigned short* pb = P + ((size_t)p << 17) + (((size_t)(b0 + wm * 64)) << 8);
#pragma unroll
  for (int nf = 0; nf < 4; nf++){
    const int col = wn * 64 + nf * 16 + l15;
    const float b3v = b3[col];
#pragma unroll
    for (int mf = 0; mf < 4; mf++){
#pragma unroll
      for (int e = 0; e < 4; e++){
        const int row = mf * 16 + (lq << 2) + e;
        pb[((size_t)row << 8) + col] = f2bf(fmaxf(c3[mf][nf][e] + b3v, 0.f));
      }
    }
  }
}

// ---------- slab reduction: out += sum_{15 slabs of i} P ----------
__global__ __launch_bounds__(256) void k_reduce(const unsigned short* __restrict__ P,
                                                float* __restrict__ out){
  int idx = blockIdx.x * 256 + threadIdx.x;     // one thread per 4 cols
  const int c4  = (idx & 63) << 2;
  const int row = idx >> 6;                     // 0..8191
  const int i   = row >> 9;
  const unsigned short* pb = P + (((size_t)(i * 15)) << 17) + (((size_t)(row & 511)) << 8) + c4;
  float s0 = 0.f, s1 = 0.f, s2 = 0.f, s3 = 0.f;
#pragma unroll
  for (int s = 0; s < 15; s++){
    ushort4 v = *(const ushort4*)(pb + ((size_t)s << 17));
    s0 += bf2f(v.x); s1 += bf2f(v.y); s2 += bf2f(v.z); s3 += bf2f(v.w);
  }
  float4* op = (float4*)(out + ((size_t)row << 8) + c4);
  float4 o = *op;
  o.x += s0; o.y += s1; o.z += s2; o.w += s3;
  *op = o;
}

// ---------- host ----------

extern "C" void kernel_launch(void* const* d_in, const int* in_sizes, int n_in,
                              void* d_out, int out_size, void* d_ws, size_t ws_size,
                              hipStream_t stream){
  const float* objs = (const float*)d_in[0];
  const float* tW1  = (const float*)d_in[1];
  const float* tb1  = (const float*)d_in[2];
  const float* tW2  = (const float*)d_in[3];
  const float* tb2  = (const float*)d_in[4];
  const float* tW3  = (const float*)d_in[5];
  const float* tb3  = (const float*)d_in[6];
  const float* iW1  = (const float*)d_in[7];
  const float* ib1  = (const float*)d_in[8];
  const float* iW2  = (const float*)d_in[9];
  const float* ib2  = (const float*)d_in[10];
  const float* iW3  = (const float*)d_in[11];
  const float* ib3  = (const float*)d_in[12];
  float* out = (float*)d_out;

  char* ws = (char*)d_ws;
  size_t off = 0;
  unsigned short* objsb  = (unsigned short*)(ws + off); off += (size_t)RR * DD * 2;        // 4 MB
  unsigned short* H1     = (unsigned short*)(ws + off); off += (size_t)RR * 512 * 2;       // 8 MB
  unsigned short* H2     = (unsigned short*)(ws + off); off += (size_t)RR * 512 * 2;       // 8 MB
  unsigned short* UVb    = (unsigned short*)(ws + off); off += (size_t)RR * 1024 * 2;      // 16 MB
  unsigned short* tW1t   = (unsigned short*)(ws + off); off += 512 * 256 * 2;
  unsigned short* tW2t   = (unsigned short*)(ws + off); off += 512 * 512 * 2;
  unsigned short* tW3t   = (unsigned short*)(ws + off); off += 256 * 512 * 2;
  unsigned short* iW1abt = (unsigned short*)(ws + off); off += 1024 * 256 * 2;
  unsigned short* iW2t   = (unsigned short*)(ws + off); off += 512 * 512 * 2;
  unsigned short* iW3t   = (unsigned short*)(ws + off); off += 256 * 512 * 2;
  float*          ib1ext = (float*)(ws + off);          off += 1024 * 4;
  unsigned short* P      = (unsigned short*)(ws + off); off += (size_t)240 * 512 * 256 * 2; // 60 MB
  (void)ws_size; (void)in_sizes; (void)n_in; (void)out_size;

  // prep: cast objs + all weight transposes (2 launches)
  k_cast4<<<dim3((RR * DD / 4 + 255) / 256), dim3(256), 0, stream>>>(objs, objsb, RR * DD / 4);
  k_prep<<<dim3(4609), dim3(256), 0, stream>>>(tW1, tW2, tW3, iW1, iW2, iW3, ib1,
                                               tW1t, tW2t, tW3t, iW1abt, iW2t, iW3t, ib1ext);

  // phase-A GEMMs
  k_gemm<256, true,  true,  false><<<dim3(RR / 64, 4), dim3(256), 0, stream>>>(objsb, tW1t, tb1, H1, nullptr, RR, 512);
  k_gemm<256, true,  false, false><<<dim3(RR / 64, 8), dim3(256), 0, stream>>>(objsb, iW1abt, ib1ext, UVb, nullptr, RR, 1024);
  k_gemm<512, true,  true,  false><<<dim3(RR / 64, 4), dim3(256), 0, stream>>>(H1, tW2t, tb2, H2, nullptr, RR, 512);
  // T path: out = relu(H2@tW3+tb3) + objs
  k_gemm<512, false, true,  true ><<<dim3(RR / 64, 2), dim3(256), 0, stream>>>(H2, tW3t, tb3, d_out, objs, RR, DD);

  // fused pair interaction -> bf16 partial slabs (no atomics)
  k_pair2<<<dim3(960), dim3(512), 0, stream>>>(UVb, iW2t, iW3t, ib2, ib3, P);

  // out += sum of 15 slabs per i
  k_reduce<<<dim3(2048), dim3(256), 0, stream>>>(P, out);
}